// Round 1
// baseline (4403.023 us; speedup 1.0000x reference)
//
#include <hip/hip_runtime.h>
#include <hip/hip_bf16.h>

typedef short s16x8 __attribute__((ext_vector_type(8)));
typedef float f32x4 __attribute__((ext_vector_type(4)));

#define B_  128
#define T_  256
#define D_  1024

// workspace layout
#define WPACK_BYTES (6144u * 2048u)            // bf16 [6144 cols][1024 k], col = gate*1024 + d
#define HBUF_BYTES  (128u * 1024u * 2u)        // h state, bf16, fragment-ordered
#define HA_OFF      (WPACK_BYTES)
#define HB_OFF      (HA_OFF + HBUF_BYTES)
#define SLOTS_OFF   (HB_OFF + HBUF_BYTES)
#define WS_NEEDED   (SLOTS_OFF + 1024u)

static __device__ __forceinline__ float sigm_f(float x) {
  float e = __builtin_amdgcn_exp2f(-1.4426950408889634f * x);
  return __builtin_amdgcn_rcpf(1.0f + e);
}
static __device__ __forceinline__ float tanh_f(float x) {
  float e = __builtin_amdgcn_exp2f(-2.8853900817779268f * x);
  return 2.0f * __builtin_amdgcn_rcpf(1.0f + e) - 1.0f;
}
static __device__ __forceinline__ unsigned short f2bf(float f) {
  return __builtin_bit_cast(unsigned short, __float2bfloat16(f));
}
static __device__ __forceinline__ float bf2f(unsigned short u) {
  return __bfloat162float(__builtin_bit_cast(__hip_bfloat16, u));
}
// fragment-ordered h layout: byte offset of element (b, k).
// A-fragment (bb, kk, MT) is the contiguous 1KB block; lane holds bytes [lane*16, lane*16+16).
static __device__ __forceinline__ unsigned hoff(int b, int k) {
  unsigned bb = (unsigned)b >> 6, mt = ((unsigned)b >> 4) & 3u, r = (unsigned)b & 15u;
  unsigned kk = (unsigned)k >> 5, g = ((unsigned)k >> 3) & 3u, k0 = (unsigned)k & 7u;
  return (((((bb * 32u + kk) * 4u + mt) * 4u + g) * 16u + r) * 8u + k0) * 2u;
}

// ---------------- prepass: pack weights (bf16, col-major-by-gate), pack x0, zero slots ----
extern "C" __global__ __launch_bounds__(256)
void gru_prepass(const float* __restrict__ x, const float* __restrict__ Wk,
                 const float* __restrict__ Wr, float* __restrict__ out,
                 char* __restrict__ ws) {
  const int W = blockIdx.x, tid = threadIdx.x;
  if (W < 3072) {
    // weight transpose+pack: Wpack[c][k] bf16, c = gate*1024 + d.
    // packed col c maps to source col c (gates 0..2 -> kernel, 3..5 -> rec_kernel at c-3072).
    const int v = W * 4 + (tid >> 6);
    const int lane = tid & 63;
    const int cb = v % 96, gk = v / 96;           // cb: 64-col block, gk: 8-k granule
    const int c = cb * 64 + lane;
    const float* src = (c < 3072) ? (Wk + c) : (Wr + (c - 3072));
    s16x8 pk;
#pragma unroll
    for (int j = 0; j < 8; ++j) {
      float val = src[(size_t)(gk * 8 + j) * 3072u];   // coalesced across lanes
      pk[j] = (short)f2bf(val);
    }
    *(s16x8*)(ws + (size_t)c * 2048u + (unsigned)gk * 16u) = pk;
  } else if (W < 3200) {
    // pack x0 -> hA (fragment layout, bf16) and copy out[:,0,:]
    const int b = W - 3072;
    const int k4 = tid * 4;
    float4 v = *(const float4*)(x + (size_t)b * D_ + k4);
    ushort4 u;
    u.x = f2bf(v.x); u.y = f2bf(v.y); u.z = f2bf(v.z); u.w = f2bf(v.w);
    *(ushort4*)(ws + HA_OFF + hoff(b, k4)) = u;
    *(float4*)(out + ((size_t)b * T_) * D_ + k4) = v;
  } else {
    if (tid < 256) ((unsigned*)(ws + SLOTS_OFF))[tid] = 0u;
  }
}

// ---------------- persistent GRU kernel: 256 wgs (1/CU), 255 steps ----------------
extern "C" __global__ __launch_bounds__(256, 1)
void gru_main(const float* __restrict__ bias, float* __restrict__ out,
              char* __restrict__ ws) {
  __shared__ f32x4 lds_red[4 * 6 * 64];   // 24 KB: per-wave K-half partials

  const int tid = threadIdx.x;
  const int w = tid >> 6, lane = tid & 63;
  const int bb = blockIdx.x >> 7;         // batch half (0,1)
  const int db = blockIdx.x & 127;        // d-block (8 h-columns)
  const int d0 = db * 8, b0 = bb * 64;
  const int kh = w & 1;                   // K half owned by this wave
  const int mh = w >> 1;                  // m-tile pair owned by this wave

  char* hA = ws + HA_OFF;
  char* hB = ws + HB_OFF;
  unsigned* slots = (unsigned*)(ws + SLOTS_OFF);
  const char* wp = ws;

  // ---- load this wave's 48 B-fragments into registers; static for all 255 steps ----
  // local col lc = gate*8 + dl (gate 0..5 = xz,xr,xh,hz,hr,hh), 3 n-tiles of 16.
  s16x8 breg[3][16];
#pragma unroll
  for (int nt = 0; nt < 3; ++nt) {
    const int lc = nt * 16 + (lane & 15);
    const int c = (lc >> 3) * 1024 + d0 + (lc & 7);
    const char* colp = wp + (size_t)c * 2048u + (unsigned)((lane >> 4) * 16);
#pragma unroll
    for (int i = 0; i < 16; ++i) {
      const int kk = kh * 16 + i;
      breg[nt][i] = *(const s16x8*)(colp + (unsigned)kk * 64u);
    }
  }

  const int dl = lane & 7;
  const float bz = bias[d0 + dl];
  const float br = bias[1024 + d0 + dl];
  const float bh = bias[2048 + d0 + dl];
  const int hi = (lane >> 3) & 1;   // which gate-triple this lane's C columns hold

  for (int t = 1; t < 256; ++t) {
    const char* hs = (t & 1) ? hA : hB;   // t=1 reads hA = packed x0
    char*       hd = (t & 1) ? hB : hA;

    // ---- A fragments for this step: coalesced 1KB frag blocks straight from L2 ----
    s16x8 areg[2][16];
#pragma unroll
    for (int i = 0; i < 16; ++i) {
      const int kk = kh * 16 + i;
      const char* ab = hs + (size_t)(((bb * 32 + kk) * 4) + mh * 2) * 1024u + (unsigned)(lane * 16);
      areg[0][i] = *(const s16x8*)(ab);
      areg[1][i] = *(const s16x8*)(ab + 1024u);
    }

    f32x4 acc[2][3];
#pragma unroll
    for (int m = 0; m < 2; ++m)
#pragma unroll
      for (int nt = 0; nt < 3; ++nt)
        acc[m][nt] = (f32x4){0.f, 0.f, 0.f, 0.f};

#pragma unroll
    for (int i = 0; i < 16; ++i) {
#pragma unroll
      for (int nt = 0; nt < 3; ++nt) {
        acc[0][nt] = __builtin_amdgcn_mfma_f32_16x16x32_bf16(areg[0][i], breg[nt][i], acc[0][nt], 0, 0, 0);
        acc[1][nt] = __builtin_amdgcn_mfma_f32_16x16x32_bf16(areg[1][i], breg[nt][i], acc[1][nt], 0, 0, 0);
      }
    }

    // ---- cross-wave K reduction (2 K-halves) via LDS ----
#pragma unroll
    for (int m = 0; m < 2; ++m)
#pragma unroll
      for (int nt = 0; nt < 3; ++nt)
        lds_red[(w * 6 + m * 3 + nt) * 64 + lane] = acc[m][nt];
    __syncthreads();

    // wave w owns m-tile MT = w; contributors are waves {w&~1, w|1} (kh=0/1, same mh)
    f32x4 g3[3];
    {
      const int wa = (w & ~1), wb2 = (w | 1);
      const int mtl = w & 1;
#pragma unroll
      for (int nt = 0; nt < 3; ++nt) {
        f32x4 pa = lds_red[(wa * 6 + mtl * 3 + nt) * 64 + lane];
        f32x4 pb = lds_red[(wb2 * 6 + mtl * 3 + nt) * 64 + lane];
        g3[nt] = pa + pb;
      }
    }

    // lane holds gates {2nt+hi}; partner lane^8 holds the complementary triple
    float o0[4], o1[4], o2[4];
#pragma unroll
    for (int j = 0; j < 4; ++j) {
      o0[j] = __shfl_xor(g3[0][j], 8);
      o1[j] = __shfl_xor(g3[1][j], 8);
      o2[j] = __shfl_xor(g3[2][j], 8);
    }

    const int d = d0 + dl;
#pragma unroll
    for (int j = 0; j < 4; ++j) {
      float xz = hi ? o0[j] : g3[0][j];
      float xh = hi ? o1[j] : g3[1][j];
      float hr = hi ? o2[j] : g3[2][j];
      float xr = hi ? g3[0][j] : o0[j];
      float hz = hi ? g3[1][j] : o1[j];
      float hh = hi ? g3[2][j] : o2[j];
      if (t == 1) { hz = 0.f; hr = 0.f; hh = 0.f; }   // h0 = 0: rec-gate matmul is garbage
      float z  = sigm_f(xz + bz + hz);
      float r  = sigm_f(xr + br + hr);
      float hc = tanh_f(xh + bh + r * hh);
      const int brow = b0 + w * 16 + (lane >> 4) * 4 + j;
      float hold = 0.f;
      if (t > 1) hold = bf2f(*(const unsigned short*)(hs + hoff(brow, d)));
      float hn = z * hold + (1.f - z) * hc;
      if (hi == 0) {
        // device-coherent state store (next step read by other XCDs)
        __hip_atomic_store((unsigned short*)(hd + hoff(brow, d)), f2bf(hn),
                           __ATOMIC_RELAXED, __HIP_MEMORY_SCOPE_AGENT);
        out[((size_t)brow * T_ + t) * D_ + d] = hn;
      }
    }

    // ---- device-wide barrier: slot store + wave0 polls all 256 slots ----
    __syncthreads();   // waits vmcnt(0): all agent-scope h stores complete (globally visible)
    if (tid == 0)
      __hip_atomic_store(&slots[blockIdx.x], (unsigned)t,
                         __ATOMIC_RELEASE, __HIP_MEMORY_SCOPE_AGENT);
    if (w == 0) {
      const unsigned* sl = slots + lane * 4;
      int guard = 0;
      do {
        unsigned s0 = __hip_atomic_load(sl + 0, __ATOMIC_RELAXED, __HIP_MEMORY_SCOPE_AGENT);
        unsigned s1 = __hip_atomic_load(sl + 1, __ATOMIC_RELAXED, __HIP_MEMORY_SCOPE_AGENT);
        unsigned s2 = __hip_atomic_load(sl + 2, __ATOMIC_RELAXED, __HIP_MEMORY_SCOPE_AGENT);
        unsigned s3 = __hip_atomic_load(sl + 3, __ATOMIC_RELAXED, __HIP_MEMORY_SCOPE_AGENT);
        bool ok = (s0 >= (unsigned)t) && (s1 >= (unsigned)t) &&
                  (s2 >= (unsigned)t) && (s3 >= (unsigned)t);
        if (__all(ok)) break;
        __builtin_amdgcn_s_sleep(1);
      } while (++guard < (1 << 20));   // safety bailout: fail loudly instead of hanging
      __builtin_amdgcn_fence(__ATOMIC_ACQUIRE, "agent");  // invalidate L1/L2 for fresh h
    }
    __syncthreads();
  }
}

extern "C" void kernel_launch(void* const* d_in, const int* in_sizes, int n_in,
                              void* d_out, int out_size, void* d_ws, size_t ws_size,
                              hipStream_t stream) {
  (void)in_sizes; (void)n_in; (void)out_size;
  if (ws_size < WS_NEEDED) return;   // fail loudly via absmax rather than corrupt
  const float* x    = (const float*)d_in[0];
  const float* Wk   = (const float*)d_in[1];
  const float* Wr   = (const float*)d_in[2];
  const float* bias = (const float*)d_in[3];
  float* out = (float*)d_out;
  char*  ws  = (char*)d_ws;

  hipLaunchKernelGGL(gru_prepass, dim3(3201), dim3(256), 0, stream, x, Wk, Wr, out, ws);
  hipLaunchKernelGGL(gru_main,    dim3(256),  dim3(256), 0, stream, bias, out, ws);
}

// Round 2
// 4136.952 us; speedup vs baseline: 1.0643x; 1.0643x over previous
//
#include <hip/hip_runtime.h>
#include <hip/hip_bf16.h>

typedef short s16x8 __attribute__((ext_vector_type(8)));
typedef float f32x4 __attribute__((ext_vector_type(4)));

#define B_  128
#define T_  256
#define D_  1024

// workspace layout
#define WPACK_BYTES (6144u * 2048u)            // bf16 [6144 cols][1024 k], col = gate*1024 + d
#define HBUF_BYTES  (128u * 1024u * 2u)        // h state, bf16, fragment-ordered
#define HA_OFF      (WPACK_BYTES)
#define HB_OFF      (HA_OFF + HBUF_BYTES)
#define SLOTS_OFF   (HB_OFF + HBUF_BYTES)      // 256 slots, padded 64B apart
#define EPOCH_OFF   (SLOTS_OFF + 256u * 64u)   // single broadcast word, own line
#define WS_NEEDED   (EPOCH_OFF + 64u)

static __device__ __forceinline__ float sigm_f(float x) {
  float e = __builtin_amdgcn_exp2f(-1.4426950408889634f * x);
  return __builtin_amdgcn_rcpf(1.0f + e);
}
static __device__ __forceinline__ float tanh_f(float x) {
  float e = __builtin_amdgcn_exp2f(-2.8853900817779268f * x);
  return 2.0f * __builtin_amdgcn_rcpf(1.0f + e) - 1.0f;
}
static __device__ __forceinline__ unsigned short f2bf(float f) {
  return __builtin_bit_cast(unsigned short, __float2bfloat16(f));
}
static __device__ __forceinline__ float bf2f(unsigned short u) {
  return __bfloat162float(__builtin_bit_cast(__hip_bfloat16, u));
}
// fragment-ordered h layout: byte offset of element (b, k).
// A-fragment (bb, kk, MT) is the contiguous 1KB block; lane holds bytes [lane*16, lane*16+16).
static __device__ __forceinline__ unsigned hoff(int b, int k) {
  unsigned bb = (unsigned)b >> 6, mt = ((unsigned)b >> 4) & 3u, r = (unsigned)b & 15u;
  unsigned kk = (unsigned)k >> 5, g = ((unsigned)k >> 3) & 3u, k0 = (unsigned)k & 7u;
  return (((((bb * 32u + kk) * 4u + mt) * 4u + g) * 16u + r) * 8u + k0) * 2u;
}

// ---------------- prepass: pack weights (bf16, col-major-by-gate), pack x0, zero barrier ----
extern "C" __global__ __launch_bounds__(256)
void gru_prepass(const float* __restrict__ x, const float* __restrict__ Wk,
                 const float* __restrict__ Wr, float* __restrict__ out,
                 char* __restrict__ ws) {
  const int W = blockIdx.x, tid = threadIdx.x;
  if (W < 3072) {
    // weight transpose+pack: Wpack[c][k] bf16, c = gate*1024 + d.
    const int v = W * 4 + (tid >> 6);
    const int lane = tid & 63;
    const int cb = v % 96, gk = v / 96;           // cb: 64-col block, gk: 8-k granule
    const int c = cb * 64 + lane;
    const float* src = (c < 3072) ? (Wk + c) : (Wr + (c - 3072));
    s16x8 pk;
#pragma unroll
    for (int j = 0; j < 8; ++j) {
      float val = src[(size_t)(gk * 8 + j) * 3072u];   // coalesced across lanes
      pk[j] = (short)f2bf(val);
    }
    *(s16x8*)(ws + (size_t)c * 2048u + (unsigned)gk * 16u) = pk;
  } else if (W < 3200) {
    // pack x0 -> hA (fragment layout, bf16) and copy out[:,0,:]
    const int b = W - 3072;
    const int k4 = tid * 4;
    float4 v = *(const float4*)(x + (size_t)b * D_ + k4);
    ushort4 u;
    u.x = f2bf(v.x); u.y = f2bf(v.y); u.z = f2bf(v.z); u.w = f2bf(v.w);
    *(ushort4*)(ws + HA_OFF + hoff(b, k4)) = u;
    *(float4*)(out + ((size_t)b * T_) * D_ + k4) = v;
  } else {
    if (tid < 256) *(unsigned*)(ws + SLOTS_OFF + (unsigned)tid * 64u) = 0u;
    if (tid == 0)  *(unsigned*)(ws + EPOCH_OFF) = 0u;
  }
}

// ---------------- persistent GRU kernel: 256 wgs (1/CU), 255 steps ----------------
extern "C" __global__ __launch_bounds__(256, 1)
void gru_main(const float* __restrict__ bias, float* __restrict__ out,
              char* __restrict__ ws) {
  __shared__ f32x4 lds_red[4 * 6 * 64];   // 24 KB: per-wave K-half partials

  const int tid = threadIdx.x;
  const int w = tid >> 6, lane = tid & 63;
  const int bb = blockIdx.x >> 7;         // batch half (0,1)
  const int db = blockIdx.x & 127;        // d-block (8 h-columns)
  const int d0 = db * 8, b0 = bb * 64;
  const int kh = w & 1;                   // K half owned by this wave
  const int mh = w >> 1;                  // m-tile pair owned by this wave

  char* hA = ws + HA_OFF;
  char* hB = ws + HB_OFF;
  unsigned* myslot = (unsigned*)(ws + SLOTS_OFF + (unsigned)blockIdx.x * 64u);
  unsigned* epoch  = (unsigned*)(ws + EPOCH_OFF);
  const char* wp = ws;

  // ---- load this wave's 48 B-fragments into registers; static for all 255 steps ----
  s16x8 breg[3][16];
#pragma unroll
  for (int nt = 0; nt < 3; ++nt) {
    const int lc = nt * 16 + (lane & 15);
    const int c = (lc >> 3) * 1024 + d0 + (lc & 7);
    const char* colp = wp + (size_t)c * 2048u + (unsigned)((lane >> 4) * 16);
#pragma unroll
    for (int i = 0; i < 16; ++i) {
      const int kk = kh * 16 + i;
      breg[nt][i] = *(const s16x8*)(colp + (unsigned)kk * 64u);
    }
  }

  const int dl = lane & 7;
  const float bz = bias[d0 + dl];
  const float br = bias[1024 + d0 + dl];
  const float bh = bias[2048 + d0 + dl];
  const int hi = (lane >> 3) & 1;   // which gate-triple this lane's C columns hold
  const int d = d0 + dl;

  for (int t = 1; t < 256; ++t) {
    const char* hs = (t & 1) ? hA : hB;   // t=1 reads hA = packed x0
    char*       hd = (t & 1) ? hB : hA;

    // ---- A fragments for this step: coalesced 1KB frag blocks (L2/IF$) ----
    s16x8 areg[2][16];
#pragma unroll
    for (int i = 0; i < 16; ++i) {
      const int kk = kh * 16 + i;
      const char* ab = hs + (size_t)(((bb * 32 + kk) * 4) + mh * 2) * 1024u + (unsigned)(lane * 16);
      areg[0][i] = *(const s16x8*)(ab);
      areg[1][i] = *(const s16x8*)(ab + 1024u);
    }

    f32x4 acc[2][3];
#pragma unroll
    for (int m = 0; m < 2; ++m)
#pragma unroll
      for (int nt = 0; nt < 3; ++nt)
        acc[m][nt] = (f32x4){0.f, 0.f, 0.f, 0.f};

#pragma unroll
    for (int i = 0; i < 16; ++i) {
#pragma unroll
      for (int nt = 0; nt < 3; ++nt) {
        acc[0][nt] = __builtin_amdgcn_mfma_f32_16x16x32_bf16(areg[0][i], breg[nt][i], acc[0][nt], 0, 0, 0);
        acc[1][nt] = __builtin_amdgcn_mfma_f32_16x16x32_bf16(areg[1][i], breg[nt][i], acc[1][nt], 0, 0, 0);
      }
    }

    // ---- cross-wave K reduction (2 K-halves) via LDS ----
#pragma unroll
    for (int m = 0; m < 2; ++m)
#pragma unroll
      for (int nt = 0; nt < 3; ++nt)
        lds_red[(w * 6 + m * 3 + nt) * 64 + lane] = acc[m][nt];
    __syncthreads();

    f32x4 g3[3];
    {
      const int wa = (w & ~1), wb2 = (w | 1);
      const int mtl = w & 1;
#pragma unroll
      for (int nt = 0; nt < 3; ++nt) {
        f32x4 pa = lds_red[(wa * 6 + mtl * 3 + nt) * 64 + lane];
        f32x4 pb = lds_red[(wb2 * 6 + mtl * 3 + nt) * 64 + lane];
        g3[nt] = pa + pb;
      }
    }

    // lane holds gates {2nt+hi}; partner lane^8 holds the complementary triple
    float o0[4], o1[4], o2[4];
#pragma unroll
    for (int j = 0; j < 4; ++j) {
      o0[j] = __shfl_xor(g3[0][j], 8);
      o1[j] = __shfl_xor(g3[1][j], 8);
      o2[j] = __shfl_xor(g3[2][j], 8);
    }

    float hn_v[4];
#pragma unroll
    for (int j = 0; j < 4; ++j) {
      float xz = hi ? o0[j] : g3[0][j];
      float xh = hi ? o1[j] : g3[1][j];
      float hr = hi ? o2[j] : g3[2][j];
      float xr = hi ? g3[0][j] : o0[j];
      float hz = hi ? g3[1][j] : o1[j];
      float hh = hi ? g3[2][j] : o2[j];
      if (t == 1) { hz = 0.f; hr = 0.f; hh = 0.f; }   // h0 = 0: rec-gate matmul is garbage
      float z  = sigm_f(xz + bz + hz);
      float r  = sigm_f(xr + br + hr);
      float hc = tanh_f(xh + bh + r * hh);
      const int brow = b0 + w * 16 + (lane >> 4) * 4 + j;
      float hold = 0.f;
      if (t > 1) hold = bf2f(*(const unsigned short*)(hs + hoff(brow, d)));
      float hn = z * hold + (1.f - z) * hc;
      hn_v[j] = hn;
      if (hi == 0)  // plain store: published by the release below
        *(unsigned short*)(hd + hoff(brow, d)) = f2bf(hn);
    }

    // ---- device-wide barrier: padded-slot release + single-word broadcast ----
    __syncthreads();   // vmcnt(0): all 4 waves' h stores are in L2
    if (tid == 0)      // release: wbl2 publishes this wg's h stores, then slot store
      __hip_atomic_store(myslot, (unsigned)t, __ATOMIC_RELEASE, __HIP_MEMORY_SCOPE_AGENT);

    // output stream (not read by anyone): nontemporal, overlaps the poll
    if (hi == 1) {
#pragma unroll
      for (int j = 0; j < 4; ++j) {
        const int brow = b0 + w * 16 + (lane >> 4) * 4 + j;
        __builtin_nontemporal_store(hn_v[j], &out[((size_t)brow * T_ + t) * D_ + d]);
      }
    }

    if (blockIdx.x == 0 && w == 0) {
      // master: aggregate 256 padded slots, then broadcast epoch
      int guard = 0;
      for (;;) {
        bool ok = true;
#pragma unroll
        for (int j = 0; j < 4; ++j) {
          unsigned s = __hip_atomic_load(
              (const unsigned*)(ws + SLOTS_OFF + (unsigned)(lane * 4 + j) * 64u),
              __ATOMIC_RELAXED, __HIP_MEMORY_SCOPE_AGENT);
          ok &= (s >= (unsigned)t);
        }
        if (__all(ok)) break;
        __builtin_amdgcn_s_sleep(1);
        if (++guard > (1 << 20)) break;   // fail loudly instead of hanging
      }
      __builtin_amdgcn_fence(__ATOMIC_ACQUIRE, "agent");  // join release chain
      if (lane == 0)
        __hip_atomic_store(epoch, (unsigned)t, __ATOMIC_RELEASE, __HIP_MEMORY_SCOPE_AGENT);
    } else if (w == 0) {
      int guard = 0;
      while (__hip_atomic_load(epoch, __ATOMIC_RELAXED, __HIP_MEMORY_SCOPE_AGENT)
             < (unsigned)t) {
        __builtin_amdgcn_s_sleep(1);
        if (++guard > (1 << 22)) break;
      }
    }
    if (w == 0)
      __builtin_amdgcn_fence(__ATOMIC_ACQUIRE, "agent");  // inv L1/L2 for fresh h
    __syncthreads();
  }
}

extern "C" void kernel_launch(void* const* d_in, const int* in_sizes, int n_in,
                              void* d_out, int out_size, void* d_ws, size_t ws_size,
                              hipStream_t stream) {
  (void)in_sizes; (void)n_in; (void)out_size;
  if (ws_size < WS_NEEDED) return;   // fail loudly via absmax rather than corrupt
  const float* x    = (const float*)d_in[0];
  const float* Wk   = (const float*)d_in[1];
  const float* Wr   = (const float*)d_in[2];
  const float* bias = (const float*)d_in[3];
  float* out = (float*)d_out;
  char*  ws  = (char*)d_ws;

  hipLaunchKernelGGL(gru_prepass, dim3(3201), dim3(256), 0, stream, x, Wk, Wr, out, ws);
  hipLaunchKernelGGL(gru_main,    dim3(256),  dim3(256), 0, stream, bias, out, ws);
}

// Round 3
// 1478.315 us; speedup vs baseline: 2.9784x; 2.7984x over previous
//
#include <hip/hip_runtime.h>
#include <hip/hip_bf16.h>

typedef short s16x8 __attribute__((ext_vector_type(8)));
typedef float f32x4 __attribute__((ext_vector_type(4)));

#define B_  128
#define T_  256
#define D_  1024

// workspace layout
#define WPACK_BYTES (6144u * 2048u)            // bf16 [6144 cols][1024 k], col = gate*1024 + d
#define HBUF_BYTES  (128u * 1024u * 2u)        // h state, bf16, fragment-ordered
#define HA_OFF      (WPACK_BYTES)
#define HB_OFF      (HA_OFF + HBUF_BYTES)
#define SLOTS_OFF   (HB_OFF + HBUF_BYTES)      // 256 slots, padded 64B apart
#define EPOCH_OFF   (SLOTS_OFF + 256u * 64u)   // 8 replicated broadcast lines
#define WS_NEEDED   (EPOCH_OFF + 8u * 64u)

static __device__ __forceinline__ float sigm_f(float x) {
  float e = __builtin_amdgcn_exp2f(-1.4426950408889634f * x);
  return __builtin_amdgcn_rcpf(1.0f + e);
}
static __device__ __forceinline__ float tanh_f(float x) {
  float e = __builtin_amdgcn_exp2f(-2.8853900817779268f * x);
  return 2.0f * __builtin_amdgcn_rcpf(1.0f + e) - 1.0f;
}
static __device__ __forceinline__ unsigned short f2bf(float f) {
  return __builtin_bit_cast(unsigned short, __float2bfloat16(f));
}
// coherent (L1+L2-bypassing) 16B load/store: h state never lives in any cache,
// so no acquire/release fences (buffer_inv / buffer_wbl2) are needed anywhere.
static __device__ __forceinline__ s16x8 ldg_coh(const char* p) {
  s16x8 v;
  asm volatile("global_load_dwordx4 %0, %1, off sc0 sc1" : "=v"(v) : "v"(p));
  return v;
}
static __device__ __forceinline__ void stg_coh(char* p, s16x8 v) {
  asm volatile("global_store_dwordx4 %0, %1, off sc0 sc1" :: "v"(p), "v"(v) : "memory");
}
// fragment-ordered h layout: byte offset of element (b, k).
static __device__ __forceinline__ unsigned hoff(int b, int k) {
  unsigned bb = (unsigned)b >> 6, mt = ((unsigned)b >> 4) & 3u, r = (unsigned)b & 15u;
  unsigned kk = (unsigned)k >> 5, g = ((unsigned)k >> 3) & 3u, k0 = (unsigned)k & 7u;
  return (((((bb * 32u + kk) * 4u + mt) * 4u + g) * 16u + r) * 8u + k0) * 2u;
}

// ---------------- prepass: pack weights (bf16), pack x0, init barrier words ----------------
extern "C" __global__ __launch_bounds__(256)
void gru_prepass(const float* __restrict__ x, const float* __restrict__ Wk,
                 const float* __restrict__ Wr, float* __restrict__ out,
                 char* __restrict__ ws) {
  const int W = blockIdx.x, tid = threadIdx.x;
  if (W < 3072) {
    const int v = W * 4 + (tid >> 6);
    const int lane = tid & 63;
    const int cb = v % 96, gk = v / 96;           // cb: 64-col block, gk: 8-k granule
    const int c = cb * 64 + lane;
    const float* src = (c < 3072) ? (Wk + c) : (Wr + (c - 3072));
    s16x8 pk;
#pragma unroll
    for (int j = 0; j < 8; ++j) {
      float val = src[(size_t)(gk * 8 + j) * 3072u];   // coalesced across lanes
      pk[j] = (short)f2bf(val);
    }
    *(s16x8*)(ws + (size_t)c * 2048u + (unsigned)gk * 16u) = pk;
  } else if (W < 3200) {
    // pack x0 -> hA (fragment layout, bf16) and copy out[:,0,:]
    const int b = W - 3072;
    const int k4 = tid * 4;
    float4 v = *(const float4*)(x + (size_t)b * D_ + k4);
    ushort4 u;
    u.x = f2bf(v.x); u.y = f2bf(v.y); u.z = f2bf(v.z); u.w = f2bf(v.w);
    *(ushort4*)(ws + HA_OFF + hoff(b, k4)) = u;
    *(float4*)(out + ((size_t)b * T_) * D_ + k4) = v;
  } else {
    if (tid < 256) *(unsigned*)(ws + SLOTS_OFF + (unsigned)tid * 64u) = 0u;
    if (tid < 8)   *(unsigned*)(ws + EPOCH_OFF + (unsigned)tid * 64u) = 0u;
  }
}

// ---------------- persistent GRU kernel: 256 wgs (1/CU), 255 steps ----------------
extern "C" __global__ __launch_bounds__(256, 1)
void gru_main(const float* __restrict__ bias, float* __restrict__ out,
              char* __restrict__ ws) {
  __shared__ f32x4 lds_red[4 * 3 * 64];                 // 12 KB: partner K-half partials
  __shared__ __align__(16) unsigned short stag[4 * 128]; // 1 KB: h store staging

  const int tid = threadIdx.x;
  const int w = tid >> 6, lane = tid & 63;
  const int bb = blockIdx.x >> 7;         // batch half (0,1)
  const int db = blockIdx.x & 127;        // d-block (8 h-columns)
  const int d0 = db * 8, b0 = bb * 64;
  const int kh = w & 1;                   // K half owned by this wave
  const int mh = w >> 1;                  // m-tile pair owned by this wave

  char* hA = ws + HA_OFF;
  char* hB = ws + HB_OFF;
  unsigned* myslot = (unsigned*)(ws + SLOTS_OFF + (unsigned)blockIdx.x * 64u);

  // ---- load this wave's 48 B-fragments into registers; static for all 255 steps ----
  s16x8 breg[3][16];
#pragma unroll
  for (int nt = 0; nt < 3; ++nt) {
    const int lc = nt * 16 + (lane & 15);
    const int c = (lc >> 3) * 1024 + d0 + (lc & 7);
    const char* colp = ws + (size_t)c * 2048u + (unsigned)((lane >> 4) * 16);
#pragma unroll
    for (int i = 0; i < 16; ++i) {
      const int kk = kh * 16 + i;
      breg[nt][i] = *(const s16x8*)(colp + (unsigned)kk * 64u);
    }
  }

  const int dl = lane & 7;
  const float bz = bias[d0 + dl];
  const float br = bias[1024 + d0 + dl];
  const float bh = bias[2048 + d0 + dl];
  const int hi = (lane >> 3) & 1;     // which gate-triple this lane's C columns hold
  const int d = d0 + dl;
  const unsigned abase_off = (unsigned)(((bb * 32 + kh * 16) * 4) + mh * 2) * 1024u;
  const unsigned hbase = hoff(b0 + w * 16, d0);   // this wave's h-slice chunk (mt = w)

  float hprev[4] = {0.f, 0.f, 0.f, 0.f};  // h_{t-1} for this lane's (brow, d): registers!

  for (int t = 1; t < 256; ++t) {
    const char* hs = (t & 1) ? hA : hB;   // t=1 reads hA = packed x0
    char*       hd = (t & 1) ? hB : hA;

    // ---- issue all 32 coherent A-fragment loads (1KB lane-linear blocks) ----
    s16x8 areg0[16], areg1[16];
    {
      const char* ab = hs + abase_off + (unsigned)(lane * 16);
#pragma unroll
      for (int i = 0; i < 16; ++i) {
        areg0[i] = ldg_coh(ab);
        areg1[i] = ldg_coh(ab + 1024u);
        ab += 4096u;
      }
    }
    __builtin_amdgcn_sched_barrier(0);

    f32x4 acc0[3], acc1[3];
#pragma unroll
    for (int nt = 0; nt < 3; ++nt) {
      acc0[nt] = (f32x4){0.f, 0.f, 0.f, 0.f};
      acc1[nt] = (f32x4){0.f, 0.f, 0.f, 0.f};
    }

    asm volatile("s_waitcnt vmcnt(16)" ::: "memory");   // frags for i=0..7 resident
    __builtin_amdgcn_sched_barrier(0);
#pragma unroll
    for (int i = 0; i < 8; ++i)
#pragma unroll
      for (int nt = 0; nt < 3; ++nt) {
        acc0[nt] = __builtin_amdgcn_mfma_f32_16x16x32_bf16(areg0[i], breg[nt][i], acc0[nt], 0, 0, 0);
        acc1[nt] = __builtin_amdgcn_mfma_f32_16x16x32_bf16(areg1[i], breg[nt][i], acc1[nt], 0, 0, 0);
      }
    asm volatile("s_waitcnt vmcnt(0)" ::: "memory");
    __builtin_amdgcn_sched_barrier(0);
#pragma unroll
    for (int i = 8; i < 16; ++i)
#pragma unroll
      for (int nt = 0; nt < 3; ++nt) {
        acc0[nt] = __builtin_amdgcn_mfma_f32_16x16x32_bf16(areg0[i], breg[nt][i], acc0[nt], 0, 0, 0);
        acc1[nt] = __builtin_amdgcn_mfma_f32_16x16x32_bf16(areg1[i], breg[nt][i], acc1[nt], 0, 0, 0);
      }

    // ---- cross-wave K reduction: each wave gives partner its half, keeps its own ----
    // wave w owns output m-tile w (acc[w&1]); partner w^1 wrote its acc[w&1] for us.
#pragma unroll
    for (int nt = 0; nt < 3; ++nt)
      lds_red[(w * 3 + nt) * 64 + lane] = (w & 1) ? acc0[nt] : acc1[nt];
    __syncthreads();
    f32x4 g3[3];
#pragma unroll
    for (int nt = 0; nt < 3; ++nt) {
      f32x4 mine = (w & 1) ? acc1[nt] : acc0[nt];
      g3[nt] = mine + lds_red[((w ^ 1) * 3 + nt) * 64 + lane];
    }

    // lane holds gates {2nt+hi}; partner lane^8 holds the complementary triple
    float o0[4], o1[4], o2[4];
#pragma unroll
    for (int j = 0; j < 4; ++j) {
      o0[j] = __shfl_xor(g3[0][j], 8);
      o1[j] = __shfl_xor(g3[1][j], 8);
      o2[j] = __shfl_xor(g3[2][j], 8);
    }

    float hn_v[4];
#pragma unroll
    for (int j = 0; j < 4; ++j) {
      float xz = hi ? o0[j] : g3[0][j];
      float xh = hi ? o1[j] : g3[1][j];
      float hr = hi ? o2[j] : g3[2][j];
      float xr = hi ? g3[0][j] : o0[j];
      float hz = hi ? g3[1][j] : o1[j];
      float hh = hi ? g3[2][j] : o2[j];
      if (t == 1) { hz = 0.f; hr = 0.f; hh = 0.f; }   // h0 = 0: rec-gate matmul is garbage
      float z  = sigm_f(xz + bz + hz);
      float r  = sigm_f(xr + br + hr);
      float hc = tanh_f(xh + bh + r * hh);
      float hn = z * hprev[j] + (1.f - z) * hc;
      hn_v[j] = hn;
      hprev[j] = hn;                       // h_{t-1} for next step, register-resident
      if (hi == 0)                          // stage bf16 h for the wide WT store
        stag[w * 128 + ((lane >> 4) * 4 + j) * 8 + dl] = f2bf(hn);
    }

    // ---- wide write-through h store: 16 lanes/wave, 16B each (wg slice = 1 KB) ----
    __syncthreads();
    if (lane < 16) {
      s16x8 pk = *(const s16x8*)&stag[w * 128 + lane * 8];
      stg_coh(hd + hbase + (unsigned)(lane * 16), pk);
    }
    asm volatile("s_waitcnt vmcnt(0)" ::: "memory");    // WT stores globally visible
    __builtin_amdgcn_sched_barrier(0);
    __syncthreads();                                     // all 4 waves' stores drained

    if (tid == 0)
      __hip_atomic_store(myslot, (unsigned)t, __ATOMIC_RELAXED, __HIP_MEMORY_SCOPE_AGENT);

    // output stream (read by nobody): nontemporal, overlaps the poll
    if (hi == 1) {
#pragma unroll
      for (int j = 0; j < 4; ++j) {
        const int brow = b0 + w * 16 + (lane >> 4) * 4 + j;
        __builtin_nontemporal_store(hn_v[j], &out[((size_t)brow * T_ + t) * D_ + d]);
      }
    }

    if (t == 255) break;                  // nothing depends on the last barrier

    if (blockIdx.x == 0 && w == 0) {
      // master: aggregate 256 padded slots, then broadcast to 8 epoch lines
      int guard = 0;
      for (;;) {
        bool ok = true;
#pragma unroll
        for (int j = 0; j < 4; ++j) {
          unsigned s = __hip_atomic_load(
              (const unsigned*)(ws + SLOTS_OFF + (unsigned)(lane * 4 + j) * 64u),
              __ATOMIC_RELAXED, __HIP_MEMORY_SCOPE_AGENT);
          ok &= (s >= (unsigned)t);
        }
        if (__all(ok)) break;
        __builtin_amdgcn_s_sleep(1);
        if (++guard > (1 << 20)) break;   // fail loudly instead of hanging
      }
      if (lane < 8)
        __hip_atomic_store((unsigned*)(ws + EPOCH_OFF + (unsigned)lane * 64u),
                           (unsigned)t, __ATOMIC_RELAXED, __HIP_MEMORY_SCOPE_AGENT);
    } else if (w == 0) {
      const unsigned* ep = (const unsigned*)(ws + EPOCH_OFF + (unsigned)((blockIdx.x >> 5) * 64));
      int guard = 0;
      while (__hip_atomic_load(ep, __ATOMIC_RELAXED, __HIP_MEMORY_SCOPE_AGENT)
             < (unsigned)t) {
        if (++guard > (1 << 22)) break;
      }
    }
    __syncthreads();
  }
}

extern "C" void kernel_launch(void* const* d_in, const int* in_sizes, int n_in,
                              void* d_out, int out_size, void* d_ws, size_t ws_size,
                              hipStream_t stream) {
  (void)in_sizes; (void)n_in; (void)out_size;
  if (ws_size < WS_NEEDED) return;   // fail loudly via absmax rather than corrupt
  const float* x    = (const float*)d_in[0];
  const float* Wk   = (const float*)d_in[1];
  const float* Wr   = (const float*)d_in[2];
  const float* bias = (const float*)d_in[3];
  float* out = (float*)d_out;
  char*  ws  = (char*)d_ws;

  hipLaunchKernelGGL(gru_prepass, dim3(3201), dim3(256), 0, stream, x, Wk, Wr, out, ws);
  hipLaunchKernelGGL(gru_main,    dim3(256),  dim3(256), 0, stream, bias, out, ws);
}